// Round 1
// baseline (3155.439 us; speedup 1.0000x reference)
//
#include <hip/hip_runtime.h>
#include <cstdint>
#include <cstddef>

#define N_NODES 100000
#define N_EDGES 3200000
#define F_IN    256
#define HID     16
#define KH      32   // K stacks (2) * HID (16)
#define C_OUT   16

// ---------------- degree histogram ----------------
__global__ void k_deg(const int* __restrict__ dst, float* __restrict__ deg) {
    int e = blockIdx.x * blockDim.x + threadIdx.x;
    if (e < N_EDGES) unsafeAtomicAdd(&deg[dst[e]], 1.0f);
}

__global__ void k_dinv(const float* __restrict__ deg, float* __restrict__ dinv) {
    int n = blockIdx.x * blockDim.x + threadIdx.x;
    if (n < N_NODES) {
        float d = deg[n];
        dinv[n] = d > 0.f ? rsqrtf(d) : 0.f;
    }
}

// ---------------- layer-1 skinny GEMM ----------------
// out columns: lane<32 -> h1[n][k][o] (init), lane>=32 -> r1[n][k][o] (root)
// weights staged in LDS as [fg][lane][4] (fg = f/4), read back as float4 per lane.
__global__ __launch_bounds__(256) void k_gemm1(
    const float* __restrict__ x, const float* __restrict__ wi,
    const float* __restrict__ wr, float* __restrict__ h1, float* __restrict__ r1) {
    __shared__ float wlds[64 * 256];  // 64KB: idx = fg*256 + l*4 + j ; f = fg*4+j
    int tid = threadIdx.x;

    // stage weights, coalesced on the GLOBAL side (consecutive tid -> consecutive addr)
    for (int i = tid; i < 2 * 4096; i += 256) {   // init_w1: [k][f][o], 8192 floats
        int k = i >> 12, f = (i >> 4) & 255, o = i & 15;
        int l = k * 16 + o;
        wlds[(f >> 2) * 256 + l * 4 + (f & 3)] = wi[i];
    }
    for (int i = tid; i < 2 * 4096; i += 256) {   // root_w1 -> lanes 32..63
        int k = i >> 12, f = (i >> 4) & 255, o = i & 15;
        int l = 32 + k * 16 + o;
        wlds[(f >> 2) * 256 + l * 4 + (f & 3)] = wr[i];
    }
    __syncthreads();

    int lane = tid & 63;
    int wid  = __builtin_amdgcn_readfirstlane(tid >> 6);
    int nwaves = gridDim.x * 4;
    const float4* wlds4 = reinterpret_cast<const float4*>(wlds);

    for (int g = blockIdx.x * 4 + wid; g < N_NODES / 8; g += nwaves) {
        int base = g * 8;
        const float* xr = x + (size_t)base * F_IN;
        float acc[8] = {0, 0, 0, 0, 0, 0, 0, 0};
        for (int fg = 0; fg < 64; ++fg) {
            float4 wv = wlds4[fg * 64 + lane];
            #pragma unroll
            for (int m = 0; m < 8; ++m) {
                float4 xv = *reinterpret_cast<const float4*>(xr + m * F_IN + fg * 4);
                acc[m] += xv.x * wv.x + xv.y * wv.y + xv.z * wv.z + xv.w * wv.w;
            }
        }
        #pragma unroll
        for (int m = 0; m < 8; ++m) {
            int n = base + m;
            if (lane < 32) h1[(size_t)n * KH + lane] = acc[m];
            else           r1[(size_t)n * KH + (lane - 32)] = acc[m];
        }
    }
}

// ---------------- edge scatter: agg[dst] += h[src] * norm ----------------
// 8 threads per edge, each does a float4 gather + 4 HW fp32 atomics.
__global__ void k_scatter(const int* __restrict__ src, const int* __restrict__ dst,
                          const float* __restrict__ dinv, const float* __restrict__ hsrc,
                          float* __restrict__ agg) {
    int t = blockIdx.x * blockDim.x + threadIdx.x;
    int e = t >> 3;
    int q = t & 7;
    if (e >= N_EDGES) return;
    int s = src[e], d = dst[e];
    float nrm = dinv[s] * dinv[d];
    float4 v = *reinterpret_cast<const float4*>(hsrc + (size_t)s * KH + q * 4);
    float* a = agg + (size_t)d * KH + q * 4;
    unsafeAtomicAdd(a + 0, v.x * nrm);
    unsafeAtomicAdd(a + 1, v.y * nrm);
    unsafeAtomicAdd(a + 2, v.z * nrm);
    unsafeAtomicAdd(a + 3, v.w * nrm);
}

// ---------------- post layer-1: act + mean + layer-2 projections ----------------
__global__ void k_post1(const float* __restrict__ agg1, const float* __restrict__ r1,
                        const float* __restrict__ b1,
                        const float* __restrict__ wi2, const float* __restrict__ wr2,
                        float* __restrict__ hout, float* __restrict__ h2,
                        float* __restrict__ r2) {
    int n = blockIdx.x * blockDim.x + threadIdx.x;
    if (n >= N_NODES) return;
    const float4* a4 = reinterpret_cast<const float4*>(agg1 + (size_t)n * KH);
    const float4* g4 = reinterpret_cast<const float4*>(r1 + (size_t)n * KH);
    float z[KH];
    #pragma unroll
    for (int q = 0; q < 8; ++q) {
        float4 a = a4[q], g = g4[q];
        z[q * 4 + 0] = a.x + g.x;
        z[q * 4 + 1] = a.y + g.y;
        z[q * 4 + 2] = a.z + g.z;
        z[q * 4 + 3] = a.w + g.w;
    }
    float h[HID];
    #pragma unroll
    for (int o = 0; o < HID; ++o) {
        float z0 = fmaxf(z[o] + b1[o], 0.f);
        float z1 = fmaxf(z[16 + o] + b1[16 + o], 0.f);
        h[o] = 0.5f * (z0 + z1);
    }
    float4* ho4 = reinterpret_cast<float4*>(hout + (size_t)n * HID);
    #pragma unroll
    for (int q = 0; q < 4; ++q)
        ho4[q] = make_float4(h[q * 4], h[q * 4 + 1], h[q * 4 + 2], h[q * 4 + 3]);
    // layer-2 projections: h2 = h @ wi2, r2 = h @ wr2   (per stack k)
    #pragma unroll
    for (int k = 0; k < 2; ++k) {
        #pragma unroll
        for (int o = 0; o < HID; ++o) {
            float ai = 0.f, ar = 0.f;
            #pragma unroll
            for (int i = 0; i < HID; ++i) {
                ai += h[i] * wi2[k * HID * HID + i * HID + o];
                ar += h[i] * wr2[k * HID * HID + i * HID + o];
            }
            h2[(size_t)n * KH + k * HID + o] = ai;
            r2[(size_t)n * KH + k * HID + o] = ar;
        }
    }
}

// ---------------- post layer-2: mean + log_softmax ----------------
__global__ void k_post2(const float* __restrict__ agg2, const float* __restrict__ r2,
                        const float* __restrict__ b2, float* __restrict__ out) {
    int n = blockIdx.x * blockDim.x + threadIdx.x;
    if (n >= N_NODES) return;
    const float4* a4 = reinterpret_cast<const float4*>(agg2 + (size_t)n * KH);
    const float4* g4 = reinterpret_cast<const float4*>(r2 + (size_t)n * KH);
    float zz[KH];
    #pragma unroll
    for (int q = 0; q < 8; ++q) {
        float4 a = a4[q], g = g4[q];
        zz[q * 4 + 0] = a.x + g.x;
        zz[q * 4 + 1] = a.y + g.y;
        zz[q * 4 + 2] = a.z + g.z;
        zz[q * 4 + 3] = a.w + g.w;
    }
    float z[C_OUT];
    float m = -1e30f;
    #pragma unroll
    for (int o = 0; o < C_OUT; ++o) {
        z[o] = 0.5f * ((zz[o] + b2[o]) + (zz[16 + o] + b2[16 + o]));
        m = fmaxf(m, z[o]);
    }
    float s = 0.f;
    #pragma unroll
    for (int o = 0; o < C_OUT; ++o) s += expf(z[o] - m);
    float ls = logf(s);
    float4* o4 = reinterpret_cast<float4*>(out + (size_t)n * C_OUT);
    #pragma unroll
    for (int q = 0; q < 4; ++q)
        o4[q] = make_float4(z[q * 4] - m - ls, z[q * 4 + 1] - m - ls,
                            z[q * 4 + 2] - m - ls, z[q * 4 + 3] - m - ls);
}

extern "C" void kernel_launch(void* const* d_in, const int* in_sizes, int n_in,
                              void* d_out, int out_size, void* d_ws, size_t ws_size,
                              hipStream_t stream) {
    const float* x   = (const float*)d_in[0];
    const int*   ei  = (const int*)d_in[1];     // [2, E] int32
    const float* wi1 = (const float*)d_in[2];
    const float* wr1 = (const float*)d_in[3];
    const float* b1  = (const float*)d_in[4];
    const float* wi2 = (const float*)d_in[5];
    const float* wr2 = (const float*)d_in[6];
    const float* b2  = (const float*)d_in[7];
    float* out = (float*)d_out;                  // [N*16 log_softmax][N*16 h]

    float* ws   = (float*)d_ws;
    float* deg  = ws;                                   // N
    float* agg1 = ws + N_NODES;                         // N*32
    float* agg2 = agg1 + (size_t)N_NODES * KH;          // N*32
    float* dinv = agg2 + (size_t)N_NODES * KH;          // N
    float* h1   = dinv + N_NODES;                       // N*32
    float* r1   = h1 + (size_t)N_NODES * KH;            // N*32
    float* h2   = r1 + (size_t)N_NODES * KH;            // N*32
    float* r2   = h2 + (size_t)N_NODES * KH;            // N*32

    const int* srcI = ei;
    const int* dstI = ei + N_EDGES;

    // zero deg + agg1 + agg2 (contiguous at ws start)
    hipMemsetAsync(ws, 0, (size_t)N_NODES * (1 + 2 * KH) * sizeof(float), stream);

    k_deg<<<(N_EDGES + 255) / 256, 256, 0, stream>>>(dstI, deg);
    k_dinv<<<(N_NODES + 255) / 256, 256, 0, stream>>>(deg, dinv);
    k_gemm1<<<625, 256, 0, stream>>>(x, wi1, wr1, h1, r1);
    k_scatter<<<(N_EDGES * 8 + 255) / 256, 256, 0, stream>>>(srcI, dstI, dinv, h1, agg1);
    k_post1<<<(N_NODES + 255) / 256, 256, 0, stream>>>(agg1, r1, b1, wi2, wr2,
                                                       out + (size_t)N_NODES * C_OUT, h2, r2);
    k_scatter<<<(N_EDGES * 8 + 255) / 256, 256, 0, stream>>>(srcI, dstI, dinv, h2, agg2);
    k_post2<<<(N_NODES + 255) / 256, 256, 0, stream>>>(agg2, r2, b2, out);
}

// Round 2
// 913.595 us; speedup vs baseline: 3.4539x; 3.4539x over previous
//
#include <hip/hip_runtime.h>
#include <cstdint>
#include <cstddef>

#define N_NODES 100000
#define N_EDGES 3200000
#define F_IN    256
#define HID     16
#define KH      32   // K stacks (2) * HID (16)
#define C_OUT   16
#define NB      391  // ceil(N_NODES/256)

// ---------------- degree histogram (int) ----------------
__global__ void k_deg(const int* __restrict__ dst, int* __restrict__ deg) {
    int e = blockIdx.x * blockDim.x + threadIdx.x;
    if (e < N_EDGES) atomicAdd(&deg[dst[e]], 1);
}

__global__ void k_dinv(const int* __restrict__ deg, float* __restrict__ dinv) {
    int n = blockIdx.x * blockDim.x + threadIdx.x;
    if (n < N_NODES) {
        int d = deg[n];
        dinv[n] = d > 0 ? rsqrtf((float)d) : 0.f;
    }
}

// ---------------- 3-kernel exclusive scan of deg -> rowptr ----------------
__global__ void k_blocksum(const int* __restrict__ deg, int* __restrict__ bsum) {
    __shared__ int s[256];
    int tid = threadIdx.x;
    int i = blockIdx.x * 256 + tid;
    s[tid] = i < N_NODES ? deg[i] : 0;
    __syncthreads();
    for (int off = 128; off > 0; off >>= 1) {
        if (tid < off) s[tid] += s[tid + off];
        __syncthreads();
    }
    if (tid == 0) bsum[blockIdx.x] = s[0];
}

__global__ void k_scanbsum(const int* __restrict__ bsum, int* __restrict__ boff,
                           int* __restrict__ rowptr) {
    __shared__ int s[512];
    int tid = threadIdx.x;
    int v = tid < NB ? bsum[tid] : 0;
    s[tid] = v;
    __syncthreads();
    for (int off = 1; off < 512; off <<= 1) {
        int t = tid >= off ? s[tid - off] : 0;
        __syncthreads();
        s[tid] += t;
        __syncthreads();
    }
    if (tid < NB) boff[tid] = s[tid] - v;   // exclusive
    if (tid == 0) rowptr[N_NODES] = N_EDGES;
}

__global__ void k_scanfinal(const int* __restrict__ deg, const int* __restrict__ boff,
                            int* __restrict__ rowptr) {
    __shared__ int s[256];
    int tid = threadIdx.x;
    int i = blockIdx.x * 256 + tid;
    int v = i < N_NODES ? deg[i] : 0;
    s[tid] = v;
    __syncthreads();
    for (int off = 1; off < 256; off <<= 1) {
        int t = tid >= off ? s[tid - off] : 0;
        __syncthreads();
        s[tid] += t;
        __syncthreads();
    }
    if (i < N_NODES) rowptr[i] = boff[blockIdx.x] + s[tid] - v;
}

// ---------------- CSR placement ----------------
__global__ void k_place(const int* __restrict__ src, const int* __restrict__ dstI,
                        const int* __restrict__ rowptr, int* __restrict__ cursor,
                        int* __restrict__ csr_src) {
    int e = blockIdx.x * blockDim.x + threadIdx.x;
    if (e >= N_EDGES) return;
    int d = dstI[e];
    int pos = rowptr[d] + atomicAdd(&cursor[d], 1);
    csr_src[pos] = src[e];
}

// ---------------- layer-1 skinny GEMM ----------------
__global__ __launch_bounds__(256) void k_gemm1(
    const float* __restrict__ x, const float* __restrict__ wi,
    const float* __restrict__ wr, float* __restrict__ h1, float* __restrict__ r1) {
    __shared__ float wlds[64 * 256];  // 64KB: idx = fg*256 + l*4 + j ; f = fg*4+j
    int tid = threadIdx.x;
    for (int i = tid; i < 2 * 4096; i += 256) {   // init_w1: [k][f][o]
        int k = i >> 12, f = (i >> 4) & 255, o = i & 15;
        int l = k * 16 + o;
        wlds[(f >> 2) * 256 + l * 4 + (f & 3)] = wi[i];
    }
    for (int i = tid; i < 2 * 4096; i += 256) {   // root_w1 -> lanes 32..63
        int k = i >> 12, f = (i >> 4) & 255, o = i & 15;
        int l = 32 + k * 16 + o;
        wlds[(f >> 2) * 256 + l * 4 + (f & 3)] = wr[i];
    }
    __syncthreads();

    int lane = tid & 63;
    int wid  = __builtin_amdgcn_readfirstlane(tid >> 6);
    int nwaves = gridDim.x * 4;
    const float4* wlds4 = reinterpret_cast<const float4*>(wlds);

    for (int g = blockIdx.x * 4 + wid; g < N_NODES / 8; g += nwaves) {
        int base = g * 8;
        const float* xr = x + (size_t)base * F_IN;
        float acc[8] = {0, 0, 0, 0, 0, 0, 0, 0};
        for (int fg = 0; fg < 64; ++fg) {
            float4 wv = wlds4[fg * 64 + lane];
            #pragma unroll
            for (int m = 0; m < 8; ++m) {
                float4 xv = *reinterpret_cast<const float4*>(xr + m * F_IN + fg * 4);
                acc[m] += xv.x * wv.x + xv.y * wv.y + xv.z * wv.z + xv.w * wv.w;
            }
        }
        #pragma unroll
        for (int m = 0; m < 8; ++m) {
            int n = base + m;
            if (lane < 32) h1[(size_t)n * KH + lane] = acc[m];
            else           r1[(size_t)n * KH + (lane - 32)] = acc[m];
        }
    }
}

// ---------------- gather aggregation: agg[n] = sum_{e in row n} h[src_e]*norm ----------------
// 8 threads per node, float4 each; CSR row loop, no atomics.
__global__ __launch_bounds__(256) void k_gather(
    const int* __restrict__ rowptr, const int* __restrict__ csr_src,
    const float* __restrict__ dinv, const float* __restrict__ h,
    float* __restrict__ agg) {
    int t = blockIdx.x * 256 + threadIdx.x;
    int n = t >> 3, q = t & 7;
    if (n >= N_NODES) return;
    int beg = rowptr[n], end = rowptr[n + 1];
    float dn = dinv[n];
    float ax = 0, ay = 0, az = 0, aw = 0;
    int j = beg;
    for (; j + 2 <= end; j += 2) {
        int s0 = csr_src[j], s1 = csr_src[j + 1];
        float n0 = dn * dinv[s0], n1 = dn * dinv[s1];
        float4 v0 = *reinterpret_cast<const float4*>(h + (size_t)s0 * KH + q * 4);
        float4 v1 = *reinterpret_cast<const float4*>(h + (size_t)s1 * KH + q * 4);
        ax += v0.x * n0 + v1.x * n1;
        ay += v0.y * n0 + v1.y * n1;
        az += v0.z * n0 + v1.z * n1;
        aw += v0.w * n0 + v1.w * n1;
    }
    if (j < end) {
        int s0 = csr_src[j];
        float n0 = dn * dinv[s0];
        float4 v0 = *reinterpret_cast<const float4*>(h + (size_t)s0 * KH + q * 4);
        ax += v0.x * n0; ay += v0.y * n0; az += v0.z * n0; aw += v0.w * n0;
    }
    *reinterpret_cast<float4*>(agg + (size_t)n * KH + q * 4) = make_float4(ax, ay, az, aw);
}

// ---------------- post layer-1: act + mean + layer-2 projections ----------------
__global__ void k_post1(const float* __restrict__ agg1, const float* __restrict__ r1,
                        const float* __restrict__ b1,
                        const float* __restrict__ wi2, const float* __restrict__ wr2,
                        float* __restrict__ hout, float* __restrict__ h2,
                        float* __restrict__ r2) {
    int n = blockIdx.x * blockDim.x + threadIdx.x;
    if (n >= N_NODES) return;
    const float4* a4 = reinterpret_cast<const float4*>(agg1 + (size_t)n * KH);
    const float4* g4 = reinterpret_cast<const float4*>(r1 + (size_t)n * KH);
    float z[KH];
    #pragma unroll
    for (int q = 0; q < 8; ++q) {
        float4 a = a4[q], g = g4[q];
        z[q * 4 + 0] = a.x + g.x;
        z[q * 4 + 1] = a.y + g.y;
        z[q * 4 + 2] = a.z + g.z;
        z[q * 4 + 3] = a.w + g.w;
    }
    float h[HID];
    #pragma unroll
    for (int o = 0; o < HID; ++o) {
        float z0 = fmaxf(z[o] + b1[o], 0.f);
        float z1 = fmaxf(z[16 + o] + b1[16 + o], 0.f);
        h[o] = 0.5f * (z0 + z1);
    }
    float4* ho4 = reinterpret_cast<float4*>(hout + (size_t)n * HID);
    #pragma unroll
    for (int q = 0; q < 4; ++q)
        ho4[q] = make_float4(h[q * 4], h[q * 4 + 1], h[q * 4 + 2], h[q * 4 + 3]);
    #pragma unroll
    for (int k = 0; k < 2; ++k) {
        #pragma unroll
        for (int o = 0; o < HID; ++o) {
            float ai = 0.f, ar = 0.f;
            #pragma unroll
            for (int i = 0; i < HID; ++i) {
                ai += h[i] * wi2[k * HID * HID + i * HID + o];
                ar += h[i] * wr2[k * HID * HID + i * HID + o];
            }
            h2[(size_t)n * KH + k * HID + o] = ai;
            r2[(size_t)n * KH + k * HID + o] = ar;
        }
    }
}

// ---------------- post layer-2: mean + log_softmax ----------------
__global__ void k_post2(const float* __restrict__ agg2, const float* __restrict__ r2,
                        const float* __restrict__ b2, float* __restrict__ out) {
    int n = blockIdx.x * blockDim.x + threadIdx.x;
    if (n >= N_NODES) return;
    const float4* a4 = reinterpret_cast<const float4*>(agg2 + (size_t)n * KH);
    const float4* g4 = reinterpret_cast<const float4*>(r2 + (size_t)n * KH);
    float zz[KH];
    #pragma unroll
    for (int q = 0; q < 8; ++q) {
        float4 a = a4[q], g = g4[q];
        zz[q * 4 + 0] = a.x + g.x;
        zz[q * 4 + 1] = a.y + g.y;
        zz[q * 4 + 2] = a.z + g.z;
        zz[q * 4 + 3] = a.w + g.w;
    }
    float z[C_OUT];
    float m = -1e30f;
    #pragma unroll
    for (int o = 0; o < C_OUT; ++o) {
        z[o] = 0.5f * ((zz[o] + b2[o]) + (zz[16 + o] + b2[16 + o]));
        m = fmaxf(m, z[o]);
    }
    float s = 0.f;
    #pragma unroll
    for (int o = 0; o < C_OUT; ++o) s += expf(z[o] - m);
    float ls = logf(s);
    float4* o4 = reinterpret_cast<float4*>(out + (size_t)n * C_OUT);
    #pragma unroll
    for (int q = 0; q < 4; ++q)
        o4[q] = make_float4(z[q * 4] - m - ls, z[q * 4 + 1] - m - ls,
                            z[q * 4 + 2] - m - ls, z[q * 4 + 3] - m - ls);
}

extern "C" void kernel_launch(void* const* d_in, const int* in_sizes, int n_in,
                              void* d_out, int out_size, void* d_ws, size_t ws_size,
                              hipStream_t stream) {
    const float* x   = (const float*)d_in[0];
    const int*   ei  = (const int*)d_in[1];     // [2, E] int32
    const float* wi1 = (const float*)d_in[2];
    const float* wr1 = (const float*)d_in[3];
    const float* b1  = (const float*)d_in[4];
    const float* wi2 = (const float*)d_in[5];
    const float* wr2 = (const float*)d_in[6];
    const float* b2  = (const float*)d_in[7];
    float* out = (float*)d_out;                  // [N*16 log_softmax][N*16 h]

    // ---- workspace layout (all element counts multiples of 4) ----
    int* degi    = (int*)d_ws;                       // N
    int* cursor  = degi + N_NODES;                   // N
    int* rowptr  = cursor + N_NODES;                 // N+1 (padded 100004)
    int* bsum    = rowptr + 100004;                  // 512
    int* boff    = bsum + 512;                       // 512
    int* csr_src = boff + 512;                       // E
    float* dinv  = (float*)(csr_src + N_EDGES);      // N
    float* h1    = dinv + N_NODES;                   // 32N
    float* r1    = h1 + (size_t)N_NODES * KH;        // 32N
    float* agg1  = r1 + (size_t)N_NODES * KH;        // 32N
    float* h2    = agg1 + (size_t)N_NODES * KH;      // 32N
    float* r2    = h2 + (size_t)N_NODES * KH;        // 32N
    float* agg2  = h1;                               // alias: h1 dead after gather1

    const int* srcI = ei;
    const int* dstI = ei + N_EDGES;

    // zero deg + cursor (contiguous)
    hipMemsetAsync(degi, 0, (size_t)2 * N_NODES * sizeof(int), stream);

    k_deg<<<(N_EDGES + 255) / 256, 256, 0, stream>>>(dstI, degi);
    k_dinv<<<(N_NODES + 255) / 256, 256, 0, stream>>>(degi, dinv);
    k_blocksum<<<NB, 256, 0, stream>>>(degi, bsum);
    k_scanbsum<<<1, 512, 0, stream>>>(bsum, boff, rowptr);
    k_scanfinal<<<NB, 256, 0, stream>>>(degi, boff, rowptr);
    k_place<<<(N_EDGES + 255) / 256, 256, 0, stream>>>(srcI, dstI, rowptr, cursor, csr_src);
    k_gemm1<<<625, 256, 0, stream>>>(x, wi1, wr1, h1, r1);
    k_gather<<<(N_NODES * 8 + 255) / 256, 256, 0, stream>>>(rowptr, csr_src, dinv, h1, agg1);
    k_post1<<<(N_NODES + 255) / 256, 256, 0, stream>>>(agg1, r1, b1, wi2, wr2,
                                                       out + (size_t)N_NODES * C_OUT, h2, r2);
    k_gather<<<(N_NODES * 8 + 255) / 256, 256, 0, stream>>>(rowptr, csr_src, dinv, h2, agg2);
    k_post2<<<(N_NODES + 255) / 256, 256, 0, stream>>>(agg2, r2, b2, out);
}

// Round 3
// 646.597 us; speedup vs baseline: 4.8801x; 1.4129x over previous
//
#include <hip/hip_runtime.h>
#include <cstdint>
#include <cstddef>

#define N_NODES 100000
#define N_EDGES 3200000
#define F_IN    256
#define HID     16
#define KH      32   // K stacks (2) * HID (16)
#define C_OUT   16
#define NB      391  // ceil(N_NODES/256)

typedef short  bf16x8 __attribute__((ext_vector_type(8)));
typedef float  f32x4  __attribute__((ext_vector_type(4)));
typedef unsigned short u16x8 __attribute__((ext_vector_type(8)));

__device__ __forceinline__ unsigned short f2bf(float f) {
    uint32_t u = __builtin_bit_cast(uint32_t, f);
    u += 0x7fffu + ((u >> 16) & 1u);      // round-to-nearest-even
    return (unsigned short)(u >> 16);
}
__device__ __forceinline__ float bf2f(unsigned short s) {
    return __builtin_bit_cast(float, (uint32_t)s << 16);
}

// ---------------- degree histogram (int) ----------------
__global__ void k_deg(const int* __restrict__ dst, int* __restrict__ deg) {
    int e = blockIdx.x * blockDim.x + threadIdx.x;
    if (e < N_EDGES) atomicAdd(&deg[dst[e]], 1);
}

__global__ void k_dinv(const int* __restrict__ deg, float* __restrict__ dinv) {
    int n = blockIdx.x * blockDim.x + threadIdx.x;
    if (n < N_NODES) {
        int d = deg[n];
        dinv[n] = d > 0 ? rsqrtf((float)d) : 0.f;
    }
}

// ---------------- 3-kernel exclusive scan of deg -> rowptr ----------------
__global__ void k_blocksum(const int* __restrict__ deg, int* __restrict__ bsum) {
    __shared__ int s[256];
    int tid = threadIdx.x;
    int i = blockIdx.x * 256 + tid;
    s[tid] = i < N_NODES ? deg[i] : 0;
    __syncthreads();
    for (int off = 128; off > 0; off >>= 1) {
        if (tid < off) s[tid] += s[tid + off];
        __syncthreads();
    }
    if (tid == 0) bsum[blockIdx.x] = s[0];
}

__global__ void k_scanbsum(const int* __restrict__ bsum, int* __restrict__ boff,
                           int* __restrict__ rowptr) {
    __shared__ int s[512];
    int tid = threadIdx.x;
    int v = tid < NB ? bsum[tid] : 0;
    s[tid] = v;
    __syncthreads();
    for (int off = 1; off < 512; off <<= 1) {
        int t = tid >= off ? s[tid - off] : 0;
        __syncthreads();
        s[tid] += t;
        __syncthreads();
    }
    if (tid < NB) boff[tid] = s[tid] - v;   // exclusive
    if (tid == 0) rowptr[N_NODES] = N_EDGES;
}

__global__ void k_scanfinal(const int* __restrict__ deg, const int* __restrict__ boff,
                            int* __restrict__ rowptr) {
    __shared__ int s[256];
    int tid = threadIdx.x;
    int i = blockIdx.x * 256 + tid;
    int v = i < N_NODES ? deg[i] : 0;
    s[tid] = v;
    __syncthreads();
    for (int off = 1; off < 256; off <<= 1) {
        int t = tid >= off ? s[tid - off] : 0;
        __syncthreads();
        s[tid] += t;
        __syncthreads();
    }
    if (i < N_NODES) rowptr[i] = boff[blockIdx.x] + s[tid] - v;
}

// ---------------- CSR placement ----------------
__global__ void k_place(const int* __restrict__ src, const int* __restrict__ dstI,
                        const int* __restrict__ rowptr, int* __restrict__ cursor,
                        int* __restrict__ csr_src) {
    int e = blockIdx.x * blockDim.x + threadIdx.x;
    if (e >= N_EDGES) return;
    int d = dstI[e];
    int pos = rowptr[d] + atomicAdd(&cursor[d], 1);
    csr_src[pos] = src[e];
}

// ---------------- layer-1 GEMM via bf16 MFMA ----------------
// C[100000 x 64] = x[100000 x 256] @ W[256 x 64]; cols 0..31 -> h1 (bf16), 32..63 -> r1 (f32)
// Per block: 64 nodes. 4 waves, wave w computes rows w*16..w*16+15, all 64 cols
// (4 colgroup accumulators). K loop: 8 steps of 32.
__global__ __launch_bounds__(256) void k_gemm1(
    const float* __restrict__ x, const float* __restrict__ wi,
    const float* __restrict__ wr, unsigned short* __restrict__ h1b,
    float* __restrict__ r1) {
    __shared__ unsigned short wt[64 * 256];     // 32KB  W^T: [col][k] bf16, slot-swizzled
    __shared__ unsigned short abuf[2][64 * 32]; // 8KB   A: [row][k] bf16, slot-swizzled

    int tid = threadIdx.x;

    // ---- stage W^T (once). col = kstack*16+o (init), 32+kstack*16+o (root); k = f.
    // 16B slot index within a col-row: slot = (k>>3) ^ (col&7); element (k&7) inside.
    for (int i = tid; i < 8192; i += 256) {
        int ksk = i >> 12, f = (i >> 4) & 255, o = i & 15;
        int col = ksk * 16 + o;
        int slot = (f >> 3) ^ (col & 7);
        wt[col * 256 + slot * 8 + (f & 7)] = f2bf(wi[i]);
    }
    for (int i = tid; i < 8192; i += 256) {
        int ksk = i >> 12, f = (i >> 4) & 255, o = i & 15;
        int col = 32 + ksk * 16 + o;
        int slot = (f >> 3) ^ (col & 7);
        wt[col * 256 + slot * 8 + (f & 7)] = f2bf(wr[i]);
    }

    // ---- A staging: thread t -> row = t>>2 (0..63), kg = t&3 (8 k's = 32B of one row)
    int row = tid >> 2;
    int kg  = tid & 3;
    int base = blockIdx.x * 64;
    int gr = min(base + row, N_NODES - 1);
    const float* xrow = x + (size_t)gr * F_IN;
    int aslot = kg ^ ((row >> 1) & 3);          // swizzle: 2-way max on frag reads
    unsigned short* awr0 = &abuf[0][row * 32 + aslot * 8];
    unsigned short* awr1 = &abuf[1][row * 32 + aslot * 8];

    // prologue: stage k-step 0 into buf0
    {
        float4 v0 = *reinterpret_cast<const float4*>(xrow + kg * 8);
        float4 v1 = *reinterpret_cast<const float4*>(xrow + kg * 8 + 4);
        u16x8 p;
        p[0] = f2bf(v0.x); p[1] = f2bf(v0.y); p[2] = f2bf(v0.z); p[3] = f2bf(v0.w);
        p[4] = f2bf(v1.x); p[5] = f2bf(v1.y); p[6] = f2bf(v1.z); p[7] = f2bf(v1.w);
        *reinterpret_cast<u16x8*>(awr0) = p;
    }
    __syncthreads();

    // ---- fragment addressing
    int lane = tid & 63;
    int wv   = tid >> 6;                    // wave 0..3
    int arow = wv * 16 + (lane & 15);
    int akg  = lane >> 4;                   // k-group 0..3 within k-step
    const unsigned short* ard0 = &abuf[0][arow * 32 + (akg ^ ((arow >> 1) & 3)) * 8];
    const unsigned short* ard1 = &abuf[1][arow * 32 + (akg ^ ((arow >> 1) & 3)) * 8];
    int col16 = lane & 15;

    f32x4 acc[4] = {{0, 0, 0, 0}, {0, 0, 0, 0}, {0, 0, 0, 0}, {0, 0, 0, 0}};

    for (int ks = 0; ks < 8; ++ks) {
        bf16x8 af = *reinterpret_cast<const bf16x8*>((ks & 1) ? ard1 : ard0);
        bf16x8 bfr[4];
        #pragma unroll
        for (int c = 0; c < 4; ++c) {
            int col = c * 16 + col16;
            int slot = (ks * 4 + akg) ^ (col & 7);
            bfr[c] = *reinterpret_cast<const bf16x8*>(&wt[col * 256 + slot * 8]);
        }
        float4 v0, v1;
        if (ks < 7) {
            v0 = *reinterpret_cast<const float4*>(xrow + (ks + 1) * 32 + kg * 8);
            v1 = *reinterpret_cast<const float4*>(xrow + (ks + 1) * 32 + kg * 8 + 4);
        }
        #pragma unroll
        for (int c = 0; c < 4; ++c)
            acc[c] = __builtin_amdgcn_mfma_f32_16x16x32_bf16(af, bfr[c], acc[c], 0, 0, 0);
        if (ks < 7) {
            u16x8 p;
            p[0] = f2bf(v0.x); p[1] = f2bf(v0.y); p[2] = f2bf(v0.z); p[3] = f2bf(v0.w);
            p[4] = f2bf(v1.x); p[5] = f2bf(v1.y); p[6] = f2bf(v1.z); p[7] = f2bf(v1.w);
            *reinterpret_cast<u16x8*>((ks & 1) ? awr0 : awr1) = p;
        }
        __syncthreads();
    }

    // ---- epilogue: D layout col = lane&15, row = (lane>>4)*4 + reg
    #pragma unroll
    for (int c = 0; c < 4; ++c) {
        #pragma unroll
        for (int r = 0; r < 4; ++r) {
            int n = base + wv * 16 + (lane >> 4) * 4 + r;
            if (n < N_NODES) {
                int col = c * 16 + col16;
                float v = acc[c][r];
                if (col < KH) h1b[(size_t)n * KH + col] = f2bf(v);
                else          r1[(size_t)n * KH + (col - KH)] = v;
            }
        }
    }
}

// ---------------- gather aggregation (bf16 table): agg[n] = sum h[src]*norm ----------------
__global__ __launch_bounds__(256) void k_gather(
    const int* __restrict__ rowptr, const int* __restrict__ csr_src,
    const float* __restrict__ dinv, const unsigned short* __restrict__ hb,
    float* __restrict__ agg) {
    int t = blockIdx.x * 256 + threadIdx.x;
    int n = t >> 3, q = t & 7;
    if (n >= N_NODES) return;
    int beg = rowptr[n], end = rowptr[n + 1];
    float dn = dinv[n];
    float ax = 0, ay = 0, az = 0, aw = 0;
    int j = beg;
    for (; j + 2 <= end; j += 2) {
        int s0 = csr_src[j], s1 = csr_src[j + 1];
        float n0 = dn * dinv[s0], n1 = dn * dinv[s1];
        ushort4 v0 = *reinterpret_cast<const ushort4*>(hb + (size_t)s0 * KH + q * 4);
        ushort4 v1 = *reinterpret_cast<const ushort4*>(hb + (size_t)s1 * KH + q * 4);
        ax += bf2f(v0.x) * n0 + bf2f(v1.x) * n1;
        ay += bf2f(v0.y) * n0 + bf2f(v1.y) * n1;
        az += bf2f(v0.z) * n0 + bf2f(v1.z) * n1;
        aw += bf2f(v0.w) * n0 + bf2f(v1.w) * n1;
    }
    if (j < end) {
        int s0 = csr_src[j];
        float n0 = dn * dinv[s0];
        ushort4 v0 = *reinterpret_cast<const ushort4*>(hb + (size_t)s0 * KH + q * 4);
        ax += bf2f(v0.x) * n0; ay += bf2f(v0.y) * n0;
        az += bf2f(v0.z) * n0; aw += bf2f(v0.w) * n0;
    }
    *reinterpret_cast<float4*>(agg + (size_t)n * KH + q * 4) = make_float4(ax, ay, az, aw);
}

// ---------------- post layer-1: act + mean + layer-2 projections ----------------
__global__ void k_post1(const float* __restrict__ agg1, const float* __restrict__ r1,
                        const float* __restrict__ b1,
                        const float* __restrict__ wi2, const float* __restrict__ wr2,
                        float* __restrict__ hout, unsigned short* __restrict__ h2b,
                        float* __restrict__ r2) {
    int n = blockIdx.x * blockDim.x + threadIdx.x;
    if (n >= N_NODES) return;
    const float4* a4 = reinterpret_cast<const float4*>(agg1 + (size_t)n * KH);
    const float4* g4 = reinterpret_cast<const float4*>(r1 + (size_t)n * KH);
    float z[KH];
    #pragma unroll
    for (int q = 0; q < 8; ++q) {
        float4 a = a4[q], g = g4[q];
        z[q * 4 + 0] = a.x + g.x;
        z[q * 4 + 1] = a.y + g.y;
        z[q * 4 + 2] = a.z + g.z;
        z[q * 4 + 3] = a.w + g.w;
    }
    float h[HID];
    #pragma unroll
    for (int o = 0; o < HID; ++o) {
        float z0 = fmaxf(z[o] + b1[o], 0.f);
        float z1 = fmaxf(z[16 + o] + b1[16 + o], 0.f);
        h[o] = 0.5f * (z0 + z1);
    }
    float4* ho4 = reinterpret_cast<float4*>(hout + (size_t)n * HID);
    #pragma unroll
    for (int q = 0; q < 4; ++q)
        ho4[q] = make_float4(h[q * 4], h[q * 4 + 1], h[q * 4 + 2], h[q * 4 + 3]);
    #pragma unroll
    for (int k = 0; k < 2; ++k) {
        #pragma unroll
        for (int o = 0; o < HID; ++o) {
            float ai = 0.f, ar = 0.f;
            #pragma unroll
            for (int i = 0; i < HID; ++i) {
                ai += h[i] * wi2[k * HID * HID + i * HID + o];
                ar += h[i] * wr2[k * HID * HID + i * HID + o];
            }
            h2b[(size_t)n * KH + k * HID + o] = f2bf(ai);
            r2[(size_t)n * KH + k * HID + o] = ar;
        }
    }
}

// ---------------- post layer-2: mean + log_softmax ----------------
__global__ void k_post2(const float* __restrict__ agg2, const float* __restrict__ r2,
                        const float* __restrict__ b2, float* __restrict__ out) {
    int n = blockIdx.x * blockDim.x + threadIdx.x;
    if (n >= N_NODES) return;
    const float4* a4 = reinterpret_cast<const float4*>(agg2 + (size_t)n * KH);
    const float4* g4 = reinterpret_cast<const float4*>(r2 + (size_t)n * KH);
    float zz[KH];
    #pragma unroll
    for (int q = 0; q < 8; ++q) {
        float4 a = a4[q], g = g4[q];
        zz[q * 4 + 0] = a.x + g.x;
        zz[q * 4 + 1] = a.y + g.y;
        zz[q * 4 + 2] = a.z + g.z;
        zz[q * 4 + 3] = a.w + g.w;
    }
    float z[C_OUT];
    float m = -1e30f;
    #pragma unroll
    for (int o = 0; o < C_OUT; ++o) {
        z[o] = 0.5f * ((zz[o] + b2[o]) + (zz[16 + o] + b2[16 + o]));
        m = fmaxf(m, z[o]);
    }
    float s = 0.f;
    #pragma unroll
    for (int o = 0; o < C_OUT; ++o) s += expf(z[o] - m);
    float ls = logf(s);
    float4* o4 = reinterpret_cast<float4*>(out + (size_t)n * C_OUT);
    #pragma unroll
    for (int q = 0; q < 4; ++q)
        o4[q] = make_float4(z[q * 4] - m - ls, z[q * 4 + 1] - m - ls,
                            z[q * 4 + 2] - m - ls, z[q * 4 + 3] - m - ls);
}

extern "C" void kernel_launch(void* const* d_in, const int* in_sizes, int n_in,
                              void* d_out, int out_size, void* d_ws, size_t ws_size,
                              hipStream_t stream) {
    const float* x   = (const float*)d_in[0];
    const int*   ei  = (const int*)d_in[1];     // [2, E] int32
    const float* wi1 = (const float*)d_in[2];
    const float* wr1 = (const float*)d_in[3];
    const float* b1  = (const float*)d_in[4];
    const float* wi2 = (const float*)d_in[5];
    const float* wr2 = (const float*)d_in[6];
    const float* b2  = (const float*)d_in[7];
    float* out = (float*)d_out;                  // [N*16 log_softmax][N*16 h]

    // ---- workspace layout ----
    int* degi    = (int*)d_ws;                       // N
    int* cursor  = degi + N_NODES;                   // N
    int* rowptr  = cursor + N_NODES;                 // N+1 (padded 100004)
    int* bsum    = rowptr + 100004;                  // 512
    int* boff    = bsum + 512;                       // 512
    int* csr_src = boff + 512;                       // E
    float* dinv  = (float*)(csr_src + N_EDGES);      // N
    float* r1    = dinv + N_NODES;                   // 32N
    float* agg1  = r1 + (size_t)N_NODES * KH;        // 32N
    float* r2    = agg1 + (size_t)N_NODES * KH;      // 32N
    float* agg2  = r2 + (size_t)N_NODES * KH;        // 32N
    unsigned short* h1b = (unsigned short*)(agg2 + (size_t)N_NODES * KH); // 32N u16
    unsigned short* h2b = h1b + (size_t)N_NODES * KH;                     // 32N u16

    const int* srcI = ei;
    const int* dstI = ei + N_EDGES;

    // zero deg + cursor (contiguous)
    hipMemsetAsync(degi, 0, (size_t)2 * N_NODES * sizeof(int), stream);

    k_deg<<<(N_EDGES + 255) / 256, 256, 0, stream>>>(dstI, degi);
    k_dinv<<<(N_NODES + 255) / 256, 256, 0, stream>>>(degi, dinv);
    k_blocksum<<<NB, 256, 0, stream>>>(degi, bsum);
    k_scanbsum<<<1, 512, 0, stream>>>(bsum, boff, rowptr);
    k_scanfinal<<<NB, 256, 0, stream>>>(degi, boff, rowptr);
    k_place<<<(N_EDGES + 255) / 256, 256, 0, stream>>>(srcI, dstI, rowptr, cursor, csr_src);
    k_gemm1<<<(N_NODES + 63) / 64, 256, 0, stream>>>(x, wi1, wr1, h1b, r1);
    k_gather<<<(N_NODES * 8 + 255) / 256, 256, 0, stream>>>(rowptr, csr_src, dinv, h1b, agg1);
    k_post1<<<(N_NODES + 255) / 256, 256, 0, stream>>>(agg1, r1, b1, wi2, wr2,
                                                       out + (size_t)N_NODES * C_OUT, h2b, r2);
    k_gather<<<(N_NODES * 8 + 255) / 256, 256, 0, stream>>>(rowptr, csr_src, dinv, h2b, agg2);
    k_post2<<<(N_NODES + 255) / 256, 256, 0, stream>>>(agg2, r2, b2, out);
}